// Round 3
// baseline (3936.013 us; speedup 1.0000x reference)
//
#include <hip/hip_runtime.h>

// ---------------------------------------------------------------------------
// 2-layer LSTM (H=51) + Linear(51,1), B=1024, T=1024, fp32.
// Design (R3): one block per batch element, 256 threads (4 waves).
//   - lane g (<204) owns gate row g: weights W_hh1[g,:], W_ih2[g,:], W_hh2[g,:]
//     persistent in VGPRs (153 fp32/lane).
//   - h1/h2 live in LDS; broadcast to all lanes via ds_read_b128 (same-address
//     across the wave -> conflict-free broadcast). Standard ds_write ->
//     __syncthreads -> ds_read semantics — NO scalar-cache coherence games
//     (R2's absmax 4.4e-2 was stale s_load data after s_dcache_inv).
//   - gates exchanged through 204-float LDS; c1/c2 in unit-lane VGPRs.
//   - 4 barriers/step: gates1 | h1 | gates2 | h2.
// ---------------------------------------------------------------------------

#define H    51
#define NG   204      // 4*H
#define TLEN 1024
#define BATCH 1024

typedef __attribute__((ext_vector_type(4))) float f4;

// dot(W[0..50], h[0..50]) with h streamed from LDS as 13 x b128 broadcast
// reads; 4 independent accumulator chains for ILP.
#define DOT51LDS(W, HPTR)                                                    \
    {                                                                        \
        _Pragma("unroll")                                                    \
        for (int i4 = 0; i4 < 12; ++i4) {                                    \
            const f4 qq = (HPTR)[i4];                                        \
            a0 += (W)[4 * i4 + 0] * qq[0];                                   \
            a1 += (W)[4 * i4 + 1] * qq[1];                                   \
            a2 += (W)[4 * i4 + 2] * qq[2];                                   \
            a3 += (W)[4 * i4 + 3] * qq[3];                                   \
        }                                                                    \
        const f4 qt = (HPTR)[12];                                            \
        a0 += (W)[48] * qt[0];                                               \
        a1 += (W)[49] * qt[1];                                               \
        a2 += (W)[50] * qt[2];                                               \
    }

__global__ __launch_bounds__(256, 2)
void lstm2_kernel(const float* __restrict__ input,
                  const float* __restrict__ W_ih1, const float* __restrict__ W_hh1,
                  const float* __restrict__ b_ih1, const float* __restrict__ b_hh1,
                  const float* __restrict__ W_ih2, const float* __restrict__ W_hh2,
                  const float* __restrict__ b_ih2, const float* __restrict__ b_hh2,
                  const float* __restrict__ W_lin, const float* __restrict__ b_lin,
                  float* __restrict__ out)
{
    const int b   = blockIdx.x;
    const int tid = threadIdx.x;
    const int g   = tid < NG ? tid : NG - 1;

    __shared__ __align__(16) float sh_h1[64];   // h1[0..50]; [51..63] stay 0
    __shared__ __align__(16) float sh_h2[64];   // h2[0..50]; [51..63] stay 0
    __shared__ float sh_g[NG];

    if (tid < 64) { sh_h1[tid] = 0.0f; sh_h2[tid] = 0.0f; }

    // persistent per-lane weight rows (VGPRs, loaded once)
    float w1[H], wi2[H], wh2[H];
#pragma unroll
    for (int k = 0; k < H; ++k) {
        w1[k]  = W_hh1[g * H + k];
        wi2[k] = W_ih2[g * H + k];
        wh2[k] = W_hh2[g * H + k];
    }
    const float wx  = W_ih1[g];
    const float bb1 = b_ih1[g] + b_hh1[g];
    const float bb2 = b_ih2[g] + b_hh2[g];

    // gate activation: i,f,o -> sigmoid ; g-rows (102..152) -> tanh.
    // unified branchless:  act(x) = am / (1 + exp(sm*x)) + bm
    const bool tg = (g >= 2 * H) && (g < 3 * H);
    const float sm = tg ? -2.0f : -1.0f;
    const float am = tg ?  2.0f :  1.0f;
    const float bm = tg ? -1.0f :  0.0f;

    const float wl   = (tid < H) ? W_lin[tid] : 0.0f;
    const float blin = b_lin[0];

    float c1 = 0.0f, c2 = 0.0f;

    const float* xrow = input + (size_t)b * TLEN;
    float*       orow = out   + (size_t)b * TLEN;

    const f4* h1v = (const f4*)sh_h1;
    const f4* h2v = (const f4*)sh_h2;

    __syncthreads();                              // h zeros visible

    for (int t = 0; t < TLEN; ++t) {
        const float x = xrow[t];                  // uniform load, consumed late

        // ---------------- layer 1 gates: needs h1_prev ----------------
        float a0 = bb1, a1 = 0.0f, a2 = 0.0f, a3 = 0.0f;
        DOT51LDS(w1, h1v);
        {
            const float pre  = (a0 + a1) + (a2 + a3) + wx * x;
            const float gate = am / (1.0f + expf(sm * pre)) + bm;
            if (tid < NG) sh_g[tid] = gate;
        }
        __syncthreads();                                        // B1

        // ---------------- layer 1 elementwise (lanes 0..50) -----------
        if (tid < H) {
            const float ig = sh_g[tid];
            const float fg = sh_g[H + tid];
            const float gg = sh_g[2 * H + tid];
            const float og = sh_g[3 * H + tid];
            c1 = fg * c1 + ig * gg;
            sh_h1[tid] = og * tanhf(c1);                        // h1_new
        }
        __syncthreads();                                        // B2

        // ---------------- layer 2 gates: h1_new and h2_prev -----------
        a0 = bb2; a1 = 0.0f; a2 = 0.0f; a3 = 0.0f;
        DOT51LDS(wi2, h1v);
        DOT51LDS(wh2, h2v);
        {
            const float pre  = (a0 + a1) + (a2 + a3);
            const float gate = am / (1.0f + expf(sm * pre)) + bm;
            if (tid < NG) sh_g[tid] = gate;
        }
        __syncthreads();                                        // B3

        // ---------------- layer 2 elementwise + linear ----------------
        float yp = 0.0f;
        if (tid < H) {
            const float ig = sh_g[tid];
            const float fg = sh_g[H + tid];
            const float gg = sh_g[2 * H + tid];
            const float og = sh_g[3 * H + tid];
            c2 = fg * c2 + ig * gg;
            const float h2n = og * tanhf(c2);
            sh_h2[tid] = h2n;                                   // h2_new
            yp = wl * h2n;
        }
        if (tid < 64) {                          // wave 0: reduce 51 terms
            yp += __shfl_down(yp, 32);
            yp += __shfl_down(yp, 16);
            yp += __shfl_down(yp, 8);
            yp += __shfl_down(yp, 4);
            yp += __shfl_down(yp, 2);
            yp += __shfl_down(yp, 1);
            if (tid == 0) orow[t] = yp + blin;
        }
        __syncthreads();                                        // B4
    }
}

extern "C" void kernel_launch(void* const* d_in, const int* in_sizes, int n_in,
                              void* d_out, int out_size, void* d_ws, size_t ws_size,
                              hipStream_t stream)
{
    const float* input = (const float*)d_in[0];
    const float* W_ih1 = (const float*)d_in[1];
    const float* W_hh1 = (const float*)d_in[2];
    const float* b_ih1 = (const float*)d_in[3];
    const float* b_hh1 = (const float*)d_in[4];
    const float* W_ih2 = (const float*)d_in[5];
    const float* W_hh2 = (const float*)d_in[6];
    const float* b_ih2 = (const float*)d_in[7];
    const float* b_hh2 = (const float*)d_in[8];
    const float* W_lin = (const float*)d_in[9];
    const float* b_lin = (const float*)d_in[10];

    float* out = (float*)d_out;

    hipLaunchKernelGGL(lstm2_kernel, dim3(BATCH), dim3(256), 0, stream,
                       input, W_ih1, W_hh1, b_ih1, b_hh1,
                       W_ih2, W_hh2, b_ih2, b_hh2, W_lin, b_lin,
                       out);
}